// Round 1
// baseline (8470.757 us; speedup 1.0000x reference)
//
#include <hip/hip_runtime.h>

typedef unsigned short u16;
typedef __attribute__((ext_vector_type(8))) short short8;
typedef __attribute__((ext_vector_type(4))) float f32x4;

#define HH 1024
#define BB 64
#define TT 512
#define G3 3072

__device__ __forceinline__ u16 f2b(float f) {
  unsigned u = __float_as_uint(f);
  unsigned r = (u + 0x7fffu + ((u >> 16) & 1u)) >> 16;
  return (u16)r;
}
__device__ __forceinline__ float b2f(u16 h) {
  return __uint_as_float(((unsigned)h) << 16);
}

// ---------------- elementwise converts / init / finalize ----------------

__global__ void f32_to_bf16_k(const float* __restrict__ s, u16* __restrict__ d, int n) {
  int stride = gridDim.x * blockDim.x * 4;
  for (int i = (blockIdx.x * blockDim.x + threadIdx.x) * 4; i < n; i += stride) {
    float4 v = *(const float4*)(s + i);
    uint2 p;
    p.x = (unsigned)f2b(v.x) | ((unsigned)f2b(v.y) << 16);
    p.y = (unsigned)f2b(v.z) | ((unsigned)f2b(v.w) << 16);
    *(uint2*)(d + i) = p;
  }
}

__global__ void init_h_k(const float* __restrict__ h0in, float* __restrict__ h0f,
                         float* __restrict__ h1f, u16* __restrict__ h0b,
                         u16* __restrict__ h1b) {
  int i = blockIdx.x * blockDim.x + threadIdx.x;
  if (i < BB * HH) {
    float a = h0in[i];
    h0f[i] = a; h0b[i] = f2b(a);
    float b = h0in[BB * HH + i];
    h1f[i] = b; h1b[i] = f2b(b);
  }
}

__global__ void finalize_k(const float* __restrict__ h0f, const float* __restrict__ h1f,
                           float* __restrict__ out) {
  int i = blockIdx.x * blockDim.x + threadIdx.x;
  if (i < BB * HH) {
    out[i] = h0f[i];
    out[BB * HH + i] = h1f[i];
  }
}

// ---------------- phase A: xg0 = bf16(x @ W_ih0^T + b_ih0) ----------------
// A: [32768][1024] bf16 row-major (K-inner), W: [3072][1024] bf16 (K-inner).
// 128x128 tile, BK=32, 4 waves (2x2 of 64x64), LDS rows padded to 80B.

__global__ __launch_bounds__(256) void gemm_xg_k(
    const u16* __restrict__ A, const u16* __restrict__ Wt,
    const float* __restrict__ bias, u16* __restrict__ C) {
  const int bm = blockIdx.x / 24;
  const int bn = blockIdx.x % 24;
  const int m0 = bm * 128, n0 = bn * 128;
  __shared__ __align__(16) u16 al[128 * 40];
  __shared__ __align__(16) u16 bl[128 * 40];
  const int tid = threadIdx.x;
  const int w = tid >> 6, l = tid & 63;
  const int wr = w >> 1, wc = w & 1;
  const int c0 = tid, c1 = tid + 256;
  const int r0 = c0 >> 2, s0 = c0 & 3, r1 = c1 >> 2, s1 = c1 & 3;

  const f32x4 fzero = {0.f, 0.f, 0.f, 0.f};
  f32x4 acc[4][4];
#pragma unroll
  for (int i = 0; i < 4; ++i)
#pragma unroll
    for (int j = 0; j < 4; ++j) acc[i][j] = fzero;

  const u16* a0p = A + (size_t)(m0 + r0) * 1024 + s0 * 8;
  const u16* a1p = A + (size_t)(m0 + r1) * 1024 + s1 * 8;
  const u16* b0p = Wt + (size_t)(n0 + r0) * 1024 + s0 * 8;
  const u16* b1p = Wt + (size_t)(n0 + r1) * 1024 + s1 * 8;

  int4 va0 = *(const int4*)(a0p);
  int4 va1 = *(const int4*)(a1p);
  int4 vb0 = *(const int4*)(b0p);
  int4 vb1 = *(const int4*)(b1p);

  for (int kt = 0; kt < 32; ++kt) {
    __syncthreads();
    *(int4*)&al[r0 * 40 + s0 * 8] = va0;
    *(int4*)&al[r1 * 40 + s1 * 8] = va1;
    *(int4*)&bl[r0 * 40 + s0 * 8] = vb0;
    *(int4*)&bl[r1 * 40 + s1 * 8] = vb1;
    __syncthreads();
    if (kt < 31) {
      va0 = *(const int4*)(a0p + (kt + 1) * 32);
      va1 = *(const int4*)(a1p + (kt + 1) * 32);
      vb0 = *(const int4*)(b0p + (kt + 1) * 32);
      vb1 = *(const int4*)(b1p + (kt + 1) * 32);
    }
    short8 af[4], bf[4];
#pragma unroll
    for (int i = 0; i < 4; ++i)
      af[i] = *(const short8*)&al[(wr * 64 + i * 16 + (l & 15)) * 40 + (l >> 4) * 8];
#pragma unroll
    for (int j = 0; j < 4; ++j)
      bf[j] = *(const short8*)&bl[(wc * 64 + j * 16 + (l & 15)) * 40 + (l >> 4) * 8];
#pragma unroll
    for (int i = 0; i < 4; ++i)
#pragma unroll
      for (int j = 0; j < 4; ++j)
        acc[i][j] = __builtin_amdgcn_mfma_f32_16x16x32_bf16(af[i], bf[j], acc[i][j], 0, 0, 0);
  }

#pragma unroll
  for (int i = 0; i < 4; ++i) {
#pragma unroll
    for (int j = 0; j < 4; ++j) {
      int col = n0 + wc * 64 + j * 16 + (l & 15);
      float bv = bias[col];
#pragma unroll
      for (int q = 0; q < 4; ++q) {
        int row = m0 + wr * 64 + i * 16 + (l >> 4) * 4 + q;
        C[(size_t)row * G3 + col] = f2b(acc[i][j][q] + bv);
      }
    }
  }
}

// ---------------- fused recurrent step ----------------
// Launch t = 0..513, grid 192 blocks x 256 threads.
//  part0 (blk 0..63):    layer0 step t      (active t<=511)
//  part1 (blk 64..127):  xg1 for step t-1   (active 1<=t<=512)
//  part2 (blk 128..191): layer1 step t-2    (active 2<=t<=513)
// All parts: M=64, 48 gate-cols (3 frags of 16), K=1024.
// Buffers at parity p0=t&1 are read, written at 1-p0.

__global__ __launch_bounds__(256) void gru_step_k(
    int t,
    const u16* __restrict__ xg0,
    const u16* __restrict__ whh0, const u16* __restrict__ wih1,
    const u16* __restrict__ whh1,
    const float* __restrict__ bhh0, const float* __restrict__ bih1,
    const float* __restrict__ bhh1,
    float* __restrict__ h0f, float* __restrict__ h1f,
    u16* __restrict__ h0b, u16* __restrict__ h1b,
    float* __restrict__ xg1) {
  const int blk = blockIdx.x;
  const int part = blk >> 6;
  if (part == 0 && t > 511) return;
  if (part == 1 && (t < 1 || t > 512)) return;
  if (part == 2 && (t < 2 || t > 513)) return;

  const int p0 = t & 1;
  const int sub = blk & 63;
  const int tid = threadIdx.x;
  const int w = tid >> 6, l = tid & 63;

  const u16* Asrc;
  const u16* Wsrc;
  int off0, off1, off2;
  if (part == 0) {
    Asrc = h0b + p0 * (BB * HH); Wsrc = whh0;
    off0 = sub * 16; off1 = HH + sub * 16; off2 = 2 * HH + sub * 16;
  } else if (part == 1) {
    Asrc = h0b + p0 * (BB * HH); Wsrc = wih1;
    off0 = sub * 48; off1 = sub * 48 + 16; off2 = sub * 48 + 32;
  } else {
    Asrc = h1b + p0 * (BB * HH); Wsrc = whh1;
    off0 = sub * 16; off1 = HH + sub * 16; off2 = 2 * HH + sub * 16;
  }

  // W slice: 48 rows x 1024 bf16 = 96KB, XOR-swizzled (elem bits 3..5 ^ row&7)
  __shared__ __align__(16) u16 wlds[48 * 1024];

  for (int i = tid; i < 6144; i += 256) {
    int r = i >> 7;
    int c = i & 127;
    int g = r >> 4;
    int wrow = (g == 0 ? off0 : (g == 1 ? off1 : off2)) + (r & 15);
    int4 v = *(const int4*)(Wsrc + (size_t)wrow * 1024 + c * 8);
    int idx = r * 1024 + ((c * 8) ^ ((r & 7) << 3));
    *(int4*)&wlds[idx] = v;
  }
  __syncthreads();

  const int lrow = l & 15;
  const int kb = (l >> 4) * 8;
  const u16* Ap = Asrc + (size_t)(w * 16 + lrow) * HH + kb;
  const int rr0 = lrow, rr1 = 16 + lrow, rr2 = 32 + lrow;
  const int sx0 = (rr0 & 7) << 3, sx1 = (rr1 & 7) << 3, sx2 = (rr2 & 7) << 3;
  const f32x4 fzero = {0.f, 0.f, 0.f, 0.f};
  f32x4 acc0 = fzero, acc1 = fzero, acc2 = fzero;

  short8 a_cur = *(const short8*)(Ap);
#pragma unroll 4
  for (int ks = 0; ks < 32; ++ks) {
    short8 a = a_cur;
    if (ks < 31) a_cur = *(const short8*)(Ap + (ks + 1) * 32);
    int ke = kb + ks * 32;
    short8 b0 = *(const short8*)&wlds[rr0 * 1024 + (ke ^ sx0)];
    short8 b1 = *(const short8*)&wlds[rr1 * 1024 + (ke ^ sx1)];
    short8 b2 = *(const short8*)&wlds[rr2 * 1024 + (ke ^ sx2)];
    acc0 = __builtin_amdgcn_mfma_f32_16x16x32_bf16(a, b0, acc0, 0, 0, 0);
    acc1 = __builtin_amdgcn_mfma_f32_16x16x32_bf16(a, b1, acc1, 0, 0, 0);
    acc2 = __builtin_amdgcn_mfma_f32_16x16x32_bf16(a, b2, acc2, 0, 0, 0);
  }

  if (part == 1) {
    float* ox = xg1 + (1 - p0) * (BB * G3);
    const int cc0 = off0 + lrow, cc1 = off1 + lrow, cc2 = off2 + lrow;
    const float bv0 = bih1[cc0], bv1 = bih1[cc1], bv2 = bih1[cc2];
#pragma unroll
    for (int q = 0; q < 4; ++q) {
      int row = w * 16 + (l >> 4) * 4 + q;
      ox[row * G3 + cc0] = acc0[q] + bv0;
      ox[row * G3 + cc1] = acc1[q] + bv1;
      ox[row * G3 + cc2] = acc2[q] + bv2;
    }
    return;
  }

  const float* hfo; float* hfn; u16* hbn; const float* bias;
  if (part == 0) {
    hfo = h0f + p0 * (BB * HH); hfn = h0f + (1 - p0) * (BB * HH);
    hbn = h0b + (1 - p0) * (BB * HH); bias = bhh0;
  } else {
    hfo = h1f + p0 * (BB * HH); hfn = h1f + (1 - p0) * (BB * HH);
    hbn = h1b + (1 - p0) * (BB * HH); bias = bhh1;
  }
  const int j = sub * 16 + lrow;
  const float br = bias[j], bz = bias[HH + j], bn_ = bias[2 * HH + j];
#pragma unroll
  for (int q = 0; q < 4; ++q) {
    int row = w * 16 + (l >> 4) * 4 + q;
    float xr, xz, xn;
    if (part == 0) {
      const u16* xp = xg0 + (size_t)(t * BB + row) * G3;
      xr = b2f(xp[j]); xz = b2f(xp[HH + j]); xn = b2f(xp[2 * HH + j]);
    } else {
      const float* xp = xg1 + p0 * (BB * G3) + row * G3;
      xr = xp[j]; xz = xp[HH + j]; xn = xp[2 * HH + j];
    }
    float rr = acc0[q] + br + xr;
    float zz = acc1[q] + bz + xz;
    float nn = acc2[q] + bn_;
    float r = 1.f / (1.f + __expf(-rr));
    float z = 1.f / (1.f + __expf(-zz));
    float n = tanhf(xn + r * nn);
    float ho = hfo[row * HH + j];
    float hv = (1.f - z) * n + z * ho;
    hfn[row * HH + j] = hv;
    hbn[row * HH + j] = f2b(hv);
  }
}

// ---------------- host ----------------

extern "C" void kernel_launch(void* const* d_in, const int* in_sizes, int n_in,
                              void* d_out, int out_size, void* d_ws, size_t ws_size,
                              hipStream_t stream) {
  const float* x   = (const float*)d_in[0];
  const float* h0  = (const float*)d_in[1];
  const float* wih = (const float*)d_in[2];
  const float* whh = (const float*)d_in[3];
  const float* bih = (const float*)d_in[4];
  const float* bhh = (const float*)d_in[5];
  float* out = (float*)d_out;

  char* ws = (char*)d_ws;
  size_t off = 0;
  auto alloc = [&](size_t bytes) -> void* {
    void* p = ws + off;
    off += (bytes + 255) & ~(size_t)255;
    return p;
  };
  u16* xbf   = (u16*)alloc((size_t)TT * BB * HH * 2);        // 64 MB
  u16* wihb  = (u16*)alloc((size_t)2 * G3 * HH * 2);         // 12.6 MB
  u16* whhb  = (u16*)alloc((size_t)2 * G3 * HH * 2);         // 12.6 MB
  u16* xg0   = (u16*)alloc((size_t)TT * BB * G3 * 2);        // 201 MB
  float* h0f = (float*)alloc((size_t)2 * BB * HH * 4);
  float* h1f = (float*)alloc((size_t)2 * BB * HH * 4);
  u16* h0b   = (u16*)alloc((size_t)2 * BB * HH * 2);
  u16* h1b   = (u16*)alloc((size_t)2 * BB * HH * 2);
  float* xg1 = (float*)alloc((size_t)2 * BB * G3 * 4);

  f32_to_bf16_k<<<2048, 256, 0, stream>>>(x, xbf, TT * BB * HH);
  f32_to_bf16_k<<<512, 256, 0, stream>>>(wih, wihb, 2 * G3 * HH);
  f32_to_bf16_k<<<512, 256, 0, stream>>>(whh, whhb, 2 * G3 * HH);
  init_h_k<<<256, 256, 0, stream>>>(h0, h0f, h1f, h0b, h1b);

  gemm_xg_k<<<6144, 256, 0, stream>>>(xbf, wihb, bih, xg0);

  for (int t = 0; t <= 513; ++t) {
    gru_step_k<<<192, 256, 0, stream>>>(t, xg0,
                                        whhb, wihb + (size_t)G3 * HH, whhb + (size_t)G3 * HH,
                                        bhh, bih + G3, bhh + G3,
                                        h0f, h1f, h0b, h1b, xg1);
  }

  finalize_k<<<256, 256, 0, stream>>>(h0f, h1f, out);
}